// Round 10
// baseline (346.282 us; speedup 1.0000x reference)
//
#include <hip/hip_runtime.h>

typedef unsigned short u16;
typedef unsigned long long u64;
typedef __attribute__((ext_vector_type(8))) short short8;   // bf16x8 MFMA fragment
typedef __attribute__((ext_vector_type(4))) float f32x4;

#define MFMA16(A,B,C) __builtin_amdgcn_mfma_f32_16x16x32_bf16(A,B,C,0,0,0)
#define NEG_INF_F (-4294967295.0f)

#define Bsz 8
#define Lsz 2048
#define Dsz 128

__device__ __forceinline__ u16 f2bf(float f){
  union { float f; unsigned u; } v; v.f = f;
  unsigned u = v.u;
  return (u16)((u + 0x7fffu + ((u >> 16) & 1u)) >> 16);
}
__device__ __forceinline__ float bf2f(u16 h){
  union { float f; unsigned u; } v; v.u = ((unsigned)h) << 16;
  return v.f;
}

// ---------------- projection: y = x @ W^T + b, Lorentz map -----------------
// z=0: q~ narrow*(2/scale) bf16 (d0=0), tq = -(2/scale)*t  fp32
// z=1: k~ narrow bf16 (d0=0),           tk = t             fp32
// z=2: v  TRANSPOSED [B][128][2048] hi+lo bf16 + per-block partial sums fp32
#define LPX 136   // bf16 pitch
#define LPY 133   // f32 pitch

__global__ __launch_bounds__(256) void proj_kernel(
    const float* __restrict__ xq, const float* __restrict__ xk, const float* __restrict__ xv,
    const float* __restrict__ Wq, const float* __restrict__ Wk, const float* __restrict__ Wv,
    const float* __restrict__ bq, const float* __restrict__ bk, const float* __restrict__ bv,
    const float* __restrict__ sq, const float* __restrict__ sk, const float* __restrict__ sv,
    const float* __restrict__ attn_scale,
    u16* __restrict__ qout, u16* __restrict__ kout,
    u16* __restrict__ vthi, u16* __restrict__ vtlo,
    float* __restrict__ tqo, float* __restrict__ tko,
    float* __restrict__ vpart)
{
  const int z = blockIdx.z;
  const float* x  = (z == 0) ? xq : (z == 1) ? xk : xv;
  const float* W  = (z == 0) ? Wq : (z == 1) ? Wk : Wv;
  const float* bb = (z == 0) ? bq : (z == 1) ? bk : bv;
  const float* ss = (z == 0) ? sq : (z == 1) ? sk : sv;

  __shared__ u16  xl[64 * LPX];
  __shared__ u16  wl[128 * LPX];
  __shared__ float yl[64 * LPY];
  __shared__ float scl[64];
  __shared__ float tml[64];

  const int t = threadIdx.x;
  const long row0 = (long)blockIdx.x * 64;

  for (int i = t; i < 128 * 128; i += 256) {
    int r = i >> 7, c = i & 127;
    wl[r * LPX + c] = f2bf(W[i]);
  }
  for (int i = t; i < 64 * 128; i += 256) {
    int r = i >> 7, c = i & 127;
    xl[r * LPX + c] = f2bf(x[row0 * 128 + i]);
  }
  __syncthreads();

  const int l = t & 63, wid = t >> 6;
  const int qr = l & 15, g = l >> 4;
  const int r0 = wid * 16;

  short8 af[4];
#pragma unroll
  for (int ks = 0; ks < 4; ks++)
    af[ks] = *(const short8*)&xl[(r0 + qr) * LPX + ks * 32 + g * 8];

  f32x4 acc[8];
#pragma unroll
  for (int jt = 0; jt < 8; jt++) acc[jt] = (f32x4){0.f, 0.f, 0.f, 0.f};

#pragma unroll
  for (int ks = 0; ks < 4; ks++) {
#pragma unroll
    for (int jt = 0; jt < 8; jt++) {
      short8 bfr = *(const short8*)&wl[(jt * 16 + qr) * LPX + ks * 32 + g * 8];
      acc[jt] = MFMA16(af[ks], bfr, acc[jt]);
    }
  }

  // bias + per-row squared-sum entirely in fragment registers
  float bbv[8];
#pragma unroll
  for (int jt = 0; jt < 8; jt++) bbv[jt] = bb[jt * 16 + qr];

  float ssq[4] = {0.f, 0.f, 0.f, 0.f};
#pragma unroll
  for (int jt = 0; jt < 8; jt++)
#pragma unroll
    for (int r = 0; r < 4; r++) {
      float yv = acc[jt][r] + bbv[jt];
      acc[jt][r] = yv;
      float s2 = yv * yv;
      if (jt == 0) s2 = (qr == 0) ? 0.f : s2;   // exclude d=0
      ssq[r] += s2;
    }
#pragma unroll
  for (int r = 0; r < 4; r++) {
    ssq[r] += __shfl_xor(ssq[r], 1);
    ssq[r] += __shfl_xor(ssq[r], 2);
    ssq[r] += __shfl_xor(ssq[r], 4);
    ssq[r] += __shfl_xor(ssq[r], 8);
  }

  const float es = __expf(ss[0]);
  const float fold = 2.0f / attn_scale[0];

  float tvv[4], sclv[4];
#pragma unroll
  for (int r = 0; r < 4; r++) {
    float y0 = __shfl(acc[0][r], l & 48);     // qr==0 lane of same g: d=0 value
    float tv = es / (1.0f + __expf(-y0)) + 1.1f;
    tvv[r] = tv;
    sclv[r] = sqrtf((tv * tv - 1.0f) / ssq[r]);
  }
  if (qr == 0) {
#pragma unroll
    for (int r = 0; r < 4; r++) {
      tml[r0 + g * 4 + r] = tvv[r];
      scl[r0 + g * 4 + r] = sclv[r];
    }
  }
#pragma unroll
  for (int jt = 0; jt < 8; jt++)
#pragma unroll
    for (int r = 0; r < 4; r++)
      yl[(r0 + g * 4 + r) * LPY + jt * 16 + qr] = acc[jt][r];
  __syncthreads();

  const long gbase = row0 * 128;
  if (z == 0) {
    for (int i = t; i < 64 * 128; i += 256) {
      int r = i >> 7, d = i & 127;
      float v = (d == 0) ? 0.f : yl[r * LPY + d] * scl[r] * fold;
      qout[gbase + i] = f2bf(v);
    }
    if (t < 64) tqo[row0 + t] = -tml[t] * fold;
  } else if (z == 1) {
    for (int i = t; i < 64 * 128; i += 256) {
      int r = i >> 7, d = i & 127;
      float v = (d == 0) ? 0.f : yl[r * LPY + d] * scl[r];
      kout[gbase + i] = f2bf(v);
    }
    if (t < 64) tko[row0 + t] = tml[t];
  } else {
    const int b = (int)(row0 >> 11);
    const int lpos = (int)(row0 & 2047);
    for (int i = t; i < 128 * 64; i += 256) {
      int d = i >> 6, r = i & 63;
      float v = (d == 0) ? tml[r] : yl[r * LPY + d] * scl[r];
      u16 hi = f2bf(v);
      float lo = v - bf2f(hi);
      long idx = ((long)(b * 128 + d)) * 2048 + lpos + r;
      vthi[idx] = hi;
      vtlo[idx] = f2bf(lo);
    }
    if (t < 128) {
      float s = 0.f;
      for (int r = 0; r < 64; r++)
        s += (t == 0) ? tml[r] : yl[r * LPY + t] * scl[r];
      int blk = (int)((row0 >> 6) & 31);
      vpart[((long)(b * 32 + blk)) * 128 + t] = s;
    }
  }
}

// ---------------- pack key-padding mask: one wave per 64-bit word -----------
__global__ __launch_bounds__(256) void pack_mask_kernel(
    const int* __restrict__ mask, u64* __restrict__ pmask)
{
  int gt = blockIdx.x * 256 + threadIdx.x;
  int w = gt >> 6;                     // word index 0..255
  int lane = gt & 63;
  if (w >= Bsz * 32) return;
  u64 word = __ballot(mask[w * 64 + lane] != 0);
  if (lane == 0) pmask[w] = word;
}

// ---------------- deterministic v-sum reduce --------------------------------
__global__ __launch_bounds__(128) void vreduce_kernel(
    const float* __restrict__ vpart, float* __restrict__ vsum)
{
  int i = blockIdx.x * 128 + threadIdx.x;   // 0 .. 1023
  int b = i >> 7, d = i & 127;
  float s = 0.f;
  for (int j = 0; j < 32; j++) s += vpart[((long)(b * 32 + j)) * 128 + d];
  vsum[i] = s;
}

// ---------------- flash attention + Lorentz epilogue ------------------------
// Block = 512 threads = TWO independent 4-wave halves of one strip (16 q-rows).
// Half A: k-tiles [0, TA), half B: [TA, nkt), TA = ceil(nkt/2) (trip counts
// differ by <=1; the short half runs one dummy iteration hitting barriers only).
// Within a half: round-9 cooperative engine (wave w QKs keys [16w,+16),
// global-per-tile max via LDS stats, shared P tile, PV d-sliced 32 d/wave,
// parity double-buffered P/stat, prefetched K/V). Epilogue: 2-way LSE merge
// (two-phase over d) + Lorentz normalize. Grid 1024 -> 4 blocks/CU x 8 waves
// = 32 waves/CU (full residency at VGPR<=64). Batch pinned to XCD (b=blk&7).
__global__ __launch_bounds__(512, 8) void flash_kernel(
    const u16* __restrict__ qb, const u16* __restrict__ kb,
    const u16* __restrict__ vthi, const u16* __restrict__ vtlo,
    const float* __restrict__ tq, const float* __restrict__ tk,
    const u64* __restrict__ pmask, const float* __restrict__ vsum,
    float* __restrict__ out)
{
  __shared__ u16  Pl[2][2][16][72];     // [half][parity][q][k]
  __shared__ float mstat[2][2][4][16];  // [half][parity][wave][q]
  __shared__ float lpart[2][4][16];     // [half][wave][q]
  __shared__ float mfin[2][16];         // [half][q]
  __shared__ float mrg[2][16][66];      // merge buffer, two-phase over d
  __shared__ float ssqL[16][17];
  __shared__ float rdenL[16];

  const int t = threadIdx.x;
  const int w8 = t >> 6;
  const int half = w8 >> 2;             // 0 or 1
  const int w = w8 & 3;                 // wave within half
  const int l = t & 63;
  const int blk = blockIdx.x;
  const int b = blk & 7;                // batch == XCD (round-robin dispatch)
  const int s = 127 - (blk >> 3);       // longest strips first
  const int q0 = s * 16;
  const int qr = l & 15, g = l >> 4;
  const int qg = q0 + qr;
  const int nkt = ((q0 + 15) >> 6) + 1; // k-tiles of 64 covering [0, q0+16)
  const int TA = (nkt + 1) >> 1;
  const int kt0 = half ? TA : 0;
  const int myN = half ? (nkt - TA) : TA;   // real tiles for this half

  const u16* qptr = qb + ((long)(b * 2048 + qg)) * 128 + g * 8;
  short8 qf[4];
#pragma unroll
  for (int ks = 0; ks < 4; ks++) qf[ks] = *(const short8*)(qptr + ks * 32);
  const float tqv = tq[b * 2048 + qg];  // already -(2/scale)*t_q

  const u16* kbase = kb + ((long)(b * 2048 + 16 * w + qr)) * 128 + g * 8;
  const u16* vhi0 = vthi + ((long)(b * 128 + 32 * w + qr)) * 2048 + g * 8;
  const u16* vhi1 = vhi0 + (long)16 * 2048;
  const u16* vlo0 = vtlo + ((long)(b * 128 + 32 * w + qr)) * 2048 + g * 8;
  const u16* vlo1 = vlo0 + (long)16 * 2048;

  float m = NEG_INF_F, lsum = 0.f;      // m: uniform within half; lsum lane-partial
  f32x4 acc[2];
  acc[0] = (f32x4){0.f, 0.f, 0.f, 0.f};
  acc[1] = (f32x4){0.f, 0.f, 0.f, 0.f};

  short8 kf[4];
  short8 vh[2][2], vl[2][2];
  if (myN > 0) {
    const u16* kp = kbase + ((long)(kt0 << 6)) * 128;
#pragma unroll
    for (int ks = 0; ks < 4; ks++) kf[ks] = *(const short8*)(kp + ks * 32);
  }

  for (int it = 0; it < TA; it++) {
    const bool real = (it < myN);
    const int kt = kt0 + it;
    const int k0 = kt << 6;
    const int p = it & 1;

    float p4[4];
    if (real) {
      // ---- segment A: PV(prev tile) + QK(this tile) + stat write ----
      __builtin_amdgcn_s_setprio(1);
      if (it > 0) {
        short8 pf0 = *(const short8*)&Pl[half][p ^ 1][qr][g * 8];
        short8 pf1 = *(const short8*)&Pl[half][p ^ 1][qr][32 + g * 8];
#pragma unroll
        for (int j = 0; j < 2; j++) {
          acc[j] = MFMA16(vh[j][0], pf0, acc[j]);
          acc[j] = MFMA16(vl[j][0], pf0, acc[j]);
          acc[j] = MFMA16(vh[j][1], pf1, acc[j]);
          acc[j] = MFMA16(vl[j][1], pf1, acc[j]);
        }
      }
      f32x4 sv = (f32x4){0.f, 0.f, 0.f, 0.f};
#pragma unroll
      for (int ks = 0; ks < 4; ks++) sv = MFMA16(kf[ks], qf[ks], sv);
      __builtin_amdgcn_s_setprio(0);

      const u64 mw = pmask[b * 32 + kt];
      f32x4 tkv = *(const f32x4*)(tk + b * 2048 + k0 + 16 * w + g * 4);
      const bool bndry = (k0 + 63 > q0);

      float tmax = NEG_INF_F;
#pragma unroll
      for (int r = 0; r < 4; r++) {
        int kl = 16 * w + g * 4 + r;
        float val = sv[r] + tqv * tkv[r];     // exact fp32 time product
        bool bad = ((mw >> kl) & 1ull) != 0ull;
        if (bndry) bad |= (k0 + kl > qg);
        val = bad ? NEG_INF_F : val;
        p4[r] = val;
        tmax = fmaxf(tmax, val);
      }
      tmax = fmaxf(tmax, __shfl_xor(tmax, 16));
      tmax = fmaxf(tmax, __shfl_xor(tmax, 32));
      if (g == 0) mstat[half][p][w][qr] = tmax;
    }
    __syncthreads();                          // B1

    if (real) {
      // ---- segment B: softmax finish + P write + prefetch ----
      float mt = fmaxf(fmaxf(mstat[half][p][0][qr], mstat[half][p][1][qr]),
                       fmaxf(mstat[half][p][2][qr], mstat[half][p][3][qr]));
      float mn = fmaxf(m, mt);
      float rr = __expf(m - mn);
      m = mn;

      float ts = 0.f;
#pragma unroll
      for (int r = 0; r < 4; r++) {
        float pv = __expf(p4[r] - mn);
        p4[r] = pv;
        ts += pv;
      }
      {
        u64 wv = (u64)f2bf(p4[0])
               | ((u64)f2bf(p4[1]) << 16)
               | ((u64)f2bf(p4[2]) << 32)
               | ((u64)f2bf(p4[3]) << 48);
        *(u64*)&Pl[half][p][qr][16 * w + g * 4] = wv;
      }
      lsum = lsum * rr + ts;
      acc[0][0] *= rr; acc[0][1] *= rr; acc[0][2] *= rr; acc[0][3] *= rr;
      acc[1][0] *= rr; acc[1][1] *= rr; acc[1][2] *= rr; acc[1][3] *= rr;

      if (it + 1 < myN) {                     // kf(t+1): flies across B2
        const u16* kp = kbase + ((long)(k0 + 64)) * 128;
#pragma unroll
        for (int ks = 0; ks < 4; ks++) kf[ks] = *(const short8*)(kp + ks * 32);
      }
#pragma unroll
      for (int h = 0; h < 2; h++) {           // V(t): consumed next segment A
        vh[0][h] = *(const short8*)(vhi0 + k0 + h * 32);
        vh[1][h] = *(const short8*)(vhi1 + k0 + h * 32);
        vl[0][h] = *(const short8*)(vlo0 + k0 + h * 32);
        vl[1][h] = *(const short8*)(vlo1 + k0 + h * 32);
      }
    }
    __syncthreads();                          // B2
  }

  // ---- final PV (last real tile of this half) ----
  if (myN > 0) {
    const int p = (myN - 1) & 1;
    short8 pf0 = *(const short8*)&Pl[half][p][qr][g * 8];
    short8 pf1 = *(const short8*)&Pl[half][p][qr][32 + g * 8];
#pragma unroll
    for (int j = 0; j < 2; j++) {
      acc[j] = MFMA16(vh[j][0], pf0, acc[j]);
      acc[j] = MFMA16(vl[j][0], pf0, acc[j]);
      acc[j] = MFMA16(vh[j][1], pf1, acc[j]);
      acc[j] = MFMA16(vl[j][1], pf1, acc[j]);
    }
  }

  // ---- publish per-half stats ----
  lsum += __shfl_xor(lsum, 16);
  lsum += __shfl_xor(lsum, 32);
  if (g == 0) lpart[half][w][qr] = lsum;
  if (w == 0 && g == 0) mfin[half][qr] = m;
  __syncthreads();

  // ---- two-phase 2-way LSE merge + Lorentz epilogue ----
  const int q = (t >> 4) & 15, seg = t & 15;  // valid for t < 256
  float av[8];
  float pp = 0.f;
  float w0s = 0.f, w1s = 0.f, invL = 0.f;
  bool mrow = false;

  // phase 0: d 0..63 (waves 0,1 of each half hold these)
  if (w < 2) {
#pragma unroll
    for (int j = 0; j < 2; j++)
      *(f32x4*)&mrg[half][qr][32 * w + 16 * j + g * 4] = acc[j];
  }
  __syncthreads();
  if (t < 256) {
    float m0 = mfin[0][q], m1 = mfin[1][q];
    float M = fmaxf(m0, m1);
    mrow = (M == NEG_INF_F);    // row fully masked -> uniform over ALL keys
    w0s = __expf(m0 - M);
    w1s = __expf(m1 - M);
    float L = w0s * (lpart[0][0][q] + lpart[0][1][q] + lpart[0][2][q] + lpart[0][3][q])
            + w1s * (lpart[1][0][q] + lpart[1][1][q] + lpart[1][2][q] + lpart[1][3][q]);
    invL = mrow ? 0.f : 1.0f / L;
    const float* vs = vsum + b * 128;
#pragma unroll
    for (int i = 0; i < 4; i++) {
      int d = seg * 4 + i;
      float O = w0s * mrg[0][q][d] + w1s * mrg[1][q][d];
      float a = mrow ? vs[d] * (1.0f / 2048.0f) : O * invL;
      av[i] = a;
      pp += (d == 0) ? -a * a : a * a;
    }
  }
  __syncthreads();
  // phase 1: d 64..127 (waves 2,3)
  if (w >= 2) {
#pragma unroll
    for (int j = 0; j < 2; j++)
      *(f32x4*)&mrg[half][qr][32 * (w - 2) + 16 * j + g * 4] = acc[j];
  }
  __syncthreads();
  if (t < 256) {
    const float* vs = vsum + b * 128;
#pragma unroll
    for (int i = 0; i < 4; i++) {
      int d = seg * 4 + i;
      float O = w0s * mrg[0][q][d] + w1s * mrg[1][q][d];
      float a = mrow ? vs[64 + d] * (1.0f / 2048.0f) : O * invL;
      av[4 + i] = a;
      pp += a * a;
    }
    ssqL[q][seg] = pp;
  }
  __syncthreads();
  if (t < 16) {
    float lor = 0.f;
    for (int j = 0; j < 16; j++) lor += ssqL[t][j];
    rdenL[t] = 1.0f / sqrtf(fmaxf(fabsf(lor), 1e-8f));
  }
  __syncthreads();
  if (t < 256) {
    const float rd = rdenL[q];
    float* op = out + ((long)(b * 2048 + q0 + q)) * 128 + seg * 4;
    f32x4 o1, o2;
    o1[0] = av[0] * rd; o1[1] = av[1] * rd; o1[2] = av[2] * rd; o1[3] = av[3] * rd;
    o2[0] = av[4] * rd; o2[1] = av[5] * rd; o2[2] = av[6] * rd; o2[3] = av[7] * rd;
    *(f32x4*)op = o1;
    *(f32x4*)(op + 64) = o2;
  }
}

// ---------------- launch ----------------------------------------------------
extern "C" void kernel_launch(void* const* d_in, const int* in_sizes, int n_in,
                              void* d_out, int out_size, void* d_ws, size_t ws_size,
                              hipStream_t stream)
{
  const float* query = (const float*)d_in[0];
  const float* key   = (const float*)d_in[1];
  const float* value = (const float*)d_in[2];
  const int*   mask  = (const int*)d_in[3];
  const float* Wq = (const float*)d_in[4];
  const float* bq = (const float*)d_in[5];
  const float* sq = (const float*)d_in[6];
  const float* Wk = (const float*)d_in[7];
  const float* bk = (const float*)d_in[8];
  const float* sk = (const float*)d_in[9];
  const float* Wv = (const float*)d_in[10];
  const float* bv = (const float*)d_in[11];
  const float* sv = (const float*)d_in[12];
  const float* attn_scale = (const float*)d_in[13];
  // d_in[14] = attn_bias: cancels in softmax, unused

  float* out = (float*)d_out;
  char* ws = (char*)d_ws;

  float* vsum  = (float*)ws;                        // 4 KB
  u64*   pmask = (u64*)(ws + 4096);                 // 2 KB (pad to 4 KB)
  float* tqa   = (float*)(ws + 8192);               // 64 KB
  float* tka   = (float*)(ws + 8192 + 65536);       // 64 KB
  float* vpart = (float*)(ws + 8192 + 131072);      // 128 KB
  char*  big   = ws + 8192 + 131072 + 131072;
  u16*   qbuf  = (u16*)big;                         // 4 MB
  u16*   kbuf  = qbuf + (size_t)16384 * 128;        // 4 MB
  u16*   vthi  = kbuf + (size_t)16384 * 128;        // 4 MB
  u16*   vtlo  = vthi + (size_t)16384 * 128;        // 4 MB

  proj_kernel<<<dim3(256, 1, 3), 256, 0, stream>>>(
      query, key, value, Wq, Wk, Wv, bq, bk, bv, sq, sk, sv, attn_scale,
      qbuf, kbuf, vthi, vtlo, tqa, tka, vpart);
  pack_mask_kernel<<<64, 256, 0, stream>>>(mask, pmask);
  vreduce_kernel<<<8, 128, 0, stream>>>(vpart, vsum);
  flash_kernel<<<1024, 512, 0, stream>>>(
      qbuf, kbuf, vthi, vtlo, tqa, tka, pmask, vsum, out);
}

// Round 11
// 164.891 us; speedup vs baseline: 2.1001x; 2.1001x over previous
//
#include <hip/hip_runtime.h>

typedef unsigned short u16;
typedef unsigned long long u64;
typedef __attribute__((ext_vector_type(8))) short short8;   // bf16x8 MFMA fragment
typedef __attribute__((ext_vector_type(4))) float f32x4;

#define MFMA16(A,B,C) __builtin_amdgcn_mfma_f32_16x16x32_bf16(A,B,C,0,0,0)
#define NEG_INF_F (-4294967295.0f)

#define Bsz 8
#define Lsz 2048
#define Dsz 128

__device__ __forceinline__ u16 f2bf(float f){
  union { float f; unsigned u; } v; v.f = f;
  unsigned u = v.u;
  return (u16)((u + 0x7fffu + ((u >> 16) & 1u)) >> 16);
}
__device__ __forceinline__ float bf2f(u16 h){
  union { float f; unsigned u; } v; v.u = ((unsigned)h) << 16;
  return v.f;
}

// ---------------- projection: y = x @ W^T + b, Lorentz map -----------------
// z=0: q~ narrow*(2/scale) bf16 (d0=0), tq = -(2/scale)*t  fp32
// z=1: k~ narrow bf16 (d0=0),           tk = t             fp32
// z=2: v  TRANSPOSED [B][128][2048] hi+lo bf16 + per-block partial sums fp32
#define LPX 136   // bf16 pitch
#define LPY 133   // f32 pitch

__global__ __launch_bounds__(256) void proj_kernel(
    const float* __restrict__ xq, const float* __restrict__ xk, const float* __restrict__ xv,
    const float* __restrict__ Wq, const float* __restrict__ Wk, const float* __restrict__ Wv,
    const float* __restrict__ bq, const float* __restrict__ bk, const float* __restrict__ bv,
    const float* __restrict__ sq, const float* __restrict__ sk, const float* __restrict__ sv,
    const float* __restrict__ attn_scale,
    u16* __restrict__ qout, u16* __restrict__ kout,
    u16* __restrict__ vthi, u16* __restrict__ vtlo,
    float* __restrict__ tqo, float* __restrict__ tko,
    float* __restrict__ vpart)
{
  const int z = blockIdx.z;
  const float* x  = (z == 0) ? xq : (z == 1) ? xk : xv;
  const float* W  = (z == 0) ? Wq : (z == 1) ? Wk : Wv;
  const float* bb = (z == 0) ? bq : (z == 1) ? bk : bv;
  const float* ss = (z == 0) ? sq : (z == 1) ? sk : sv;

  __shared__ u16  xl[64 * LPX];
  __shared__ u16  wl[128 * LPX];
  __shared__ float yl[64 * LPY];
  __shared__ float scl[64];
  __shared__ float tml[64];

  const int t = threadIdx.x;
  const long row0 = (long)blockIdx.x * 64;

  for (int i = t; i < 128 * 128; i += 256) {
    int r = i >> 7, c = i & 127;
    wl[r * LPX + c] = f2bf(W[i]);
  }
  for (int i = t; i < 64 * 128; i += 256) {
    int r = i >> 7, c = i & 127;
    xl[r * LPX + c] = f2bf(x[row0 * 128 + i]);
  }
  __syncthreads();

  const int l = t & 63, wid = t >> 6;
  const int qr = l & 15, g = l >> 4;
  const int r0 = wid * 16;

  short8 af[4];
#pragma unroll
  for (int ks = 0; ks < 4; ks++)
    af[ks] = *(const short8*)&xl[(r0 + qr) * LPX + ks * 32 + g * 8];

  f32x4 acc[8];
#pragma unroll
  for (int jt = 0; jt < 8; jt++) acc[jt] = (f32x4){0.f, 0.f, 0.f, 0.f};

#pragma unroll
  for (int ks = 0; ks < 4; ks++) {
#pragma unroll
    for (int jt = 0; jt < 8; jt++) {
      short8 bfr = *(const short8*)&wl[(jt * 16 + qr) * LPX + ks * 32 + g * 8];
      acc[jt] = MFMA16(af[ks], bfr, acc[jt]);
    }
  }

  // bias + per-row squared-sum entirely in fragment registers
  float bbv[8];
#pragma unroll
  for (int jt = 0; jt < 8; jt++) bbv[jt] = bb[jt * 16 + qr];

  float ssq[4] = {0.f, 0.f, 0.f, 0.f};
#pragma unroll
  for (int jt = 0; jt < 8; jt++)
#pragma unroll
    for (int r = 0; r < 4; r++) {
      float yv = acc[jt][r] + bbv[jt];
      acc[jt][r] = yv;
      float s2 = yv * yv;
      if (jt == 0) s2 = (qr == 0) ? 0.f : s2;   // exclude d=0
      ssq[r] += s2;
    }
#pragma unroll
  for (int r = 0; r < 4; r++) {
    ssq[r] += __shfl_xor(ssq[r], 1);
    ssq[r] += __shfl_xor(ssq[r], 2);
    ssq[r] += __shfl_xor(ssq[r], 4);
    ssq[r] += __shfl_xor(ssq[r], 8);
  }

  const float es = __expf(ss[0]);
  const float fold = 2.0f / attn_scale[0];

  float tvv[4], sclv[4];
#pragma unroll
  for (int r = 0; r < 4; r++) {
    float y0 = __shfl(acc[0][r], l & 48);     // qr==0 lane of same g: d=0 value
    float tv = es / (1.0f + __expf(-y0)) + 1.1f;
    tvv[r] = tv;
    sclv[r] = sqrtf((tv * tv - 1.0f) / ssq[r]);
  }
  if (qr == 0) {
#pragma unroll
    for (int r = 0; r < 4; r++) {
      tml[r0 + g * 4 + r] = tvv[r];
      scl[r0 + g * 4 + r] = sclv[r];
    }
  }
#pragma unroll
  for (int jt = 0; jt < 8; jt++)
#pragma unroll
    for (int r = 0; r < 4; r++)
      yl[(r0 + g * 4 + r) * LPY + jt * 16 + qr] = acc[jt][r];
  __syncthreads();

  const long gbase = row0 * 128;
  if (z == 0) {
    for (int i = t; i < 64 * 128; i += 256) {
      int r = i >> 7, d = i & 127;
      float v = (d == 0) ? 0.f : yl[r * LPY + d] * scl[r] * fold;
      qout[gbase + i] = f2bf(v);
    }
    if (t < 64) tqo[row0 + t] = -tml[t] * fold;
  } else if (z == 1) {
    for (int i = t; i < 64 * 128; i += 256) {
      int r = i >> 7, d = i & 127;
      float v = (d == 0) ? 0.f : yl[r * LPY + d] * scl[r];
      kout[gbase + i] = f2bf(v);
    }
    if (t < 64) tko[row0 + t] = tml[t];
  } else {
    const int b = (int)(row0 >> 11);
    const int lpos = (int)(row0 & 2047);
    for (int i = t; i < 128 * 64; i += 256) {
      int d = i >> 6, r = i & 63;
      float v = (d == 0) ? tml[r] : yl[r * LPY + d] * scl[r];
      u16 hi = f2bf(v);
      float lo = v - bf2f(hi);
      long idx = ((long)(b * 128 + d)) * 2048 + lpos + r;
      vthi[idx] = hi;
      vtlo[idx] = f2bf(lo);
    }
    if (t < 128) {
      float s = 0.f;
      for (int r = 0; r < 64; r++)
        s += (t == 0) ? tml[r] : yl[r * LPY + t] * scl[r];
      int blk = (int)((row0 >> 6) & 31);
      vpart[((long)(b * 32 + blk)) * 128 + t] = s;
    }
  }
}

// ---------------- pack key-padding mask: one wave per 64-bit word -----------
__global__ __launch_bounds__(256) void pack_mask_kernel(
    const int* __restrict__ mask, u64* __restrict__ pmask)
{
  int gt = blockIdx.x * 256 + threadIdx.x;
  int w = gt >> 6;                     // word index 0..255
  int lane = gt & 63;
  if (w >= Bsz * 32) return;
  u64 word = __ballot(mask[w * 64 + lane] != 0);
  if (lane == 0) pmask[w] = word;
}

// ---------------- deterministic v-sum reduce --------------------------------
__global__ __launch_bounds__(128) void vreduce_kernel(
    const float* __restrict__ vpart, float* __restrict__ vsum)
{
  int i = blockIdx.x * 128 + threadIdx.x;   // 0 .. 1023
  int b = i >> 7, d = i & 127;
  float s = 0.f;
  for (int j = 0; j < 32; j++) s += vpart[((long)(b * 32 + j)) * 128 + d];
  vsum[i] = s;
}

// ---------------- flash attention + Lorentz epilogue ------------------------
// Block = 512 threads = TWO independent 4-wave halves of one strip (16 q-rows).
// Half A: k-tiles [0, TA), half B: [TA, nkt), TA = ceil(nkt/2). Within a half:
// cooperative engine (wave w QKs keys [16w,+16), global-per-tile max via LDS
// stats, shared P tile, PV d-sliced 32 d/wave, parity double-buffered P/stat,
// prefetched K/V). Epilogue: 2-way LSE merge + Lorentz normalize.
// __launch_bounds__(512,4): 128-reg budget -- the engine naturally allocates
// ~64 VGPR (round 9), so no spills AND hardware can still co-schedule 8
// waves/SIMD (round 10 proved residency). Batch pinned to XCD (b=blk&7).
__global__ __launch_bounds__(512, 4) void flash_kernel(
    const u16* __restrict__ qb, const u16* __restrict__ kb,
    const u16* __restrict__ vthi, const u16* __restrict__ vtlo,
    const float* __restrict__ tq, const float* __restrict__ tk,
    const u64* __restrict__ pmask, const float* __restrict__ vsum,
    float* __restrict__ out)
{
  __shared__ u16  Pl[2][2][16][72];     // [half][parity][q][k]
  __shared__ float mstat[2][2][4][16];  // [half][parity][wave][q]
  __shared__ float lpart[2][4][16];     // [half][wave][q]
  __shared__ float mfin[2][16];         // [half][q]
  __shared__ float mrg[2][16][66];      // merge buffer, two-phase over d
  __shared__ float ssqL[16][17];
  __shared__ float rdenL[16];

  const int t = threadIdx.x;
  const int w8 = t >> 6;
  const int half = w8 >> 2;             // 0 or 1
  const int w = w8 & 3;                 // wave within half
  const int l = t & 63;
  const int blk = blockIdx.x;
  const int b = blk & 7;                // batch == XCD (round-robin dispatch)
  const int s = 127 - (blk >> 3);       // longest strips first
  const int q0 = s * 16;
  const int qr = l & 15, g = l >> 4;
  const int qg = q0 + qr;
  const int nkt = ((q0 + 15) >> 6) + 1; // k-tiles of 64 covering [0, q0+16)
  const int TA = (nkt + 1) >> 1;
  const int kt0 = half ? TA : 0;
  const int myN = half ? (nkt - TA) : TA;   // real tiles for this half

  const u16* qptr = qb + ((long)(b * 2048 + qg)) * 128 + g * 8;
  short8 qf[4];
#pragma unroll
  for (int ks = 0; ks < 4; ks++) qf[ks] = *(const short8*)(qptr + ks * 32);
  const float tqv = tq[b * 2048 + qg];  // already -(2/scale)*t_q

  const u16* kbase = kb + ((long)(b * 2048 + 16 * w + qr)) * 128 + g * 8;
  const u16* vhi0 = vthi + ((long)(b * 128 + 32 * w + qr)) * 2048 + g * 8;
  const u16* vhi1 = vhi0 + (long)16 * 2048;
  const u16* vlo0 = vtlo + ((long)(b * 128 + 32 * w + qr)) * 2048 + g * 8;
  const u16* vlo1 = vlo0 + (long)16 * 2048;

  float m = NEG_INF_F, lsum = 0.f;      // m: uniform within half; lsum lane-partial
  f32x4 acc[2];
  acc[0] = (f32x4){0.f, 0.f, 0.f, 0.f};
  acc[1] = (f32x4){0.f, 0.f, 0.f, 0.f};

  short8 kf[4];
  short8 vh[2][2], vl[2][2];
  if (myN > 0) {
    const u16* kp = kbase + ((long)(kt0 << 6)) * 128;
#pragma unroll
    for (int ks = 0; ks < 4; ks++) kf[ks] = *(const short8*)(kp + ks * 32);
  }

  for (int it = 0; it < TA; it++) {
    const bool real = (it < myN);
    const int kt = kt0 + it;
    const int k0 = kt << 6;
    const int p = it & 1;

    float p4[4];
    if (real) {
      // ---- segment A: PV(prev tile) + QK(this tile) + stat write ----
      __builtin_amdgcn_s_setprio(1);
      if (it > 0) {
        short8 pf0 = *(const short8*)&Pl[half][p ^ 1][qr][g * 8];
        short8 pf1 = *(const short8*)&Pl[half][p ^ 1][qr][32 + g * 8];
#pragma unroll
        for (int j = 0; j < 2; j++) {
          acc[j] = MFMA16(vh[j][0], pf0, acc[j]);
          acc[j] = MFMA16(vl[j][0], pf0, acc[j]);
          acc[j] = MFMA16(vh[j][1], pf1, acc[j]);
          acc[j] = MFMA16(vl[j][1], pf1, acc[j]);
        }
      }
      f32x4 sv = (f32x4){0.f, 0.f, 0.f, 0.f};
#pragma unroll
      for (int ks = 0; ks < 4; ks++) sv = MFMA16(kf[ks], qf[ks], sv);
      __builtin_amdgcn_s_setprio(0);

      const u64 mw = pmask[b * 32 + kt];
      f32x4 tkv = *(const f32x4*)(tk + b * 2048 + k0 + 16 * w + g * 4);
      const bool bndry = (k0 + 63 > q0);

      float tmax = NEG_INF_F;
#pragma unroll
      for (int r = 0; r < 4; r++) {
        int kl = 16 * w + g * 4 + r;
        float val = sv[r] + tqv * tkv[r];     // exact fp32 time product
        bool bad = ((mw >> kl) & 1ull) != 0ull;
        if (bndry) bad |= (k0 + kl > qg);
        val = bad ? NEG_INF_F : val;
        p4[r] = val;
        tmax = fmaxf(tmax, val);
      }
      tmax = fmaxf(tmax, __shfl_xor(tmax, 16));
      tmax = fmaxf(tmax, __shfl_xor(tmax, 32));
      if (g == 0) mstat[half][p][w][qr] = tmax;
    }
    __syncthreads();                          // B1

    if (real) {
      // ---- segment B: softmax finish + P write + prefetch ----
      float mt = fmaxf(fmaxf(mstat[half][p][0][qr], mstat[half][p][1][qr]),
                       fmaxf(mstat[half][p][2][qr], mstat[half][p][3][qr]));
      float mn = fmaxf(m, mt);
      float rr = __expf(m - mn);
      m = mn;

      float ts = 0.f;
#pragma unroll
      for (int r = 0; r < 4; r++) {
        float pv = __expf(p4[r] - mn);
        p4[r] = pv;
        ts += pv;
      }
      {
        u64 wv = (u64)f2bf(p4[0])
               | ((u64)f2bf(p4[1]) << 16)
               | ((u64)f2bf(p4[2]) << 32)
               | ((u64)f2bf(p4[3]) << 48);
        *(u64*)&Pl[half][p][qr][16 * w + g * 4] = wv;
      }
      lsum = lsum * rr + ts;
      acc[0][0] *= rr; acc[0][1] *= rr; acc[0][2] *= rr; acc[0][3] *= rr;
      acc[1][0] *= rr; acc[1][1] *= rr; acc[1][2] *= rr; acc[1][3] *= rr;

      if (it + 1 < myN) {                     // kf(t+1): flies across B2
        const u16* kp = kbase + ((long)(k0 + 64)) * 128;
#pragma unroll
        for (int ks = 0; ks < 4; ks++) kf[ks] = *(const short8*)(kp + ks * 32);
      }
#pragma unroll
      for (int h = 0; h < 2; h++) {           // V(t): consumed next segment A
        vh[0][h] = *(const short8*)(vhi0 + k0 + h * 32);
        vh[1][h] = *(const short8*)(vhi1 + k0 + h * 32);
        vl[0][h] = *(const short8*)(vlo0 + k0 + h * 32);
        vl[1][h] = *(const short8*)(vlo1 + k0 + h * 32);
      }
    }
    __syncthreads();                          // B2
  }

  // ---- final PV (last real tile of this half) ----
  if (myN > 0) {
    const int p = (myN - 1) & 1;
    short8 pf0 = *(const short8*)&Pl[half][p][qr][g * 8];
    short8 pf1 = *(const short8*)&Pl[half][p][qr][32 + g * 8];
#pragma unroll
    for (int j = 0; j < 2; j++) {
      acc[j] = MFMA16(vh[j][0], pf0, acc[j]);
      acc[j] = MFMA16(vl[j][0], pf0, acc[j]);
      acc[j] = MFMA16(vh[j][1], pf1, acc[j]);
      acc[j] = MFMA16(vl[j][1], pf1, acc[j]);
    }
  }

  // ---- publish per-half stats ----
  lsum += __shfl_xor(lsum, 16);
  lsum += __shfl_xor(lsum, 32);
  if (g == 0) lpart[half][w][qr] = lsum;
  if (w == 0 && g == 0) mfin[half][qr] = m;
  __syncthreads();

  // ---- two-phase 2-way LSE merge + Lorentz epilogue ----
  const int q = (t >> 4) & 15, seg = t & 15;  // valid for t < 256
  float av[8];
  float pp = 0.f;
  float w0s = 0.f, w1s = 0.f, invL = 0.f;
  bool mrow = false;

  // phase 0: d 0..63 (waves 0,1 of each half hold these)
  if (w < 2) {
#pragma unroll
    for (int j = 0; j < 2; j++)
      *(f32x4*)&mrg[half][qr][32 * w + 16 * j + g * 4] = acc[j];
  }
  __syncthreads();
  if (t < 256) {
    float m0 = mfin[0][q], m1 = mfin[1][q];
    float M = fmaxf(m0, m1);
    mrow = (M == NEG_INF_F);    // row fully masked -> uniform over ALL keys
    w0s = __expf(m0 - M);
    w1s = __expf(m1 - M);
    float L = w0s * (lpart[0][0][q] + lpart[0][1][q] + lpart[0][2][q] + lpart[0][3][q])
            + w1s * (lpart[1][0][q] + lpart[1][1][q] + lpart[1][2][q] + lpart[1][3][q]);
    invL = mrow ? 0.f : 1.0f / L;
    const float* vs = vsum + b * 128;
#pragma unroll
    for (int i = 0; i < 4; i++) {
      int d = seg * 4 + i;
      float O = w0s * mrg[0][q][d] + w1s * mrg[1][q][d];
      float a = mrow ? vs[d] * (1.0f / 2048.0f) : O * invL;
      av[i] = a;
      pp += (d == 0) ? -a * a : a * a;
    }
  }
  __syncthreads();
  // phase 1: d 64..127 (waves 2,3)
  if (w >= 2) {
#pragma unroll
    for (int j = 0; j < 2; j++)
      *(f32x4*)&mrg[half][qr][32 * (w - 2) + 16 * j + g * 4] = acc[j];
  }
  __syncthreads();
  if (t < 256) {
    const float* vs = vsum + b * 128;
#pragma unroll
    for (int i = 0; i < 4; i++) {
      int d = seg * 4 + i;
      float O = w0s * mrg[0][q][d] + w1s * mrg[1][q][d];
      float a = mrow ? vs[64 + d] * (1.0f / 2048.0f) : O * invL;
      av[4 + i] = a;
      pp += a * a;
    }
    ssqL[q][seg] = pp;
  }
  __syncthreads();
  if (t < 16) {
    float lor = 0.f;
    for (int j = 0; j < 16; j++) lor += ssqL[t][j];
    rdenL[t] = 1.0f / sqrtf(fmaxf(fabsf(lor), 1e-8f));
  }
  __syncthreads();
  if (t < 256) {
    const float rd = rdenL[q];
    float* op = out + ((long)(b * 2048 + q0 + q)) * 128 + seg * 4;
    f32x4 o1, o2;
    o1[0] = av[0] * rd; o1[1] = av[1] * rd; o1[2] = av[2] * rd; o1[3] = av[3] * rd;
    o2[0] = av[4] * rd; o2[1] = av[5] * rd; o2[2] = av[6] * rd; o2[3] = av[7] * rd;
    *(f32x4*)op = o1;
    *(f32x4*)(op + 64) = o2;
  }
}

// ---------------- launch ----------------------------------------------------
extern "C" void kernel_launch(void* const* d_in, const int* in_sizes, int n_in,
                              void* d_out, int out_size, void* d_ws, size_t ws_size,
                              hipStream_t stream)
{
  const float* query = (const float*)d_in[0];
  const float* key   = (const float*)d_in[1];
  const float* value = (const float*)d_in[2];
  const int*   mask  = (const int*)d_in[3];
  const float* Wq = (const float*)d_in[4];
  const float* bq = (const float*)d_in[5];
  const float* sq = (const float*)d_in[6];
  const float* Wk = (const float*)d_in[7];
  const float* bk = (const float*)d_in[8];
  const float* sk = (const float*)d_in[9];
  const float* Wv = (const float*)d_in[10];
  const float* bv = (const float*)d_in[11];
  const float* sv = (const float*)d_in[12];
  const float* attn_scale = (const float*)d_in[13];
  // d_in[14] = attn_bias: cancels in softmax, unused

  float* out = (float*)d_out;
  char* ws = (char*)d_ws;

  float* vsum  = (float*)ws;                        // 4 KB
  u64*   pmask = (u64*)(ws + 4096);                 // 2 KB (pad to 4 KB)
  float* tqa   = (float*)(ws + 8192);               // 64 KB
  float* tka   = (float*)(ws + 8192 + 65536);       // 64 KB
  float* vpart = (float*)(ws + 8192 + 131072);      // 128 KB
  char*  big   = ws + 8192 + 131072 + 131072;
  u16*   qbuf  = (u16*)big;                         // 4 MB
  u16*   kbuf  = qbuf + (size_t)16384 * 128;        // 4 MB
  u16*   vthi  = kbuf + (size_t)16384 * 128;        // 4 MB
  u16*   vtlo  = vthi + (size_t)16384 * 128;        // 4 MB

  proj_kernel<<<dim3(256, 1, 3), 256, 0, stream>>>(
      query, key, value, Wq, Wk, Wv, bq, bk, bv, sq, sk, sv, attn_scale,
      qbuf, kbuf, vthi, vtlo, tqa, tka, vpart);
  pack_mask_kernel<<<64, 256, 0, stream>>>(mask, pmask);
  vreduce_kernel<<<8, 128, 0, stream>>>(vpart, vsum);
  flash_kernel<<<1024, 512, 0, stream>>>(
      qbuf, kbuf, vthi, vtlo, tqa, tka, pmask, vsum, out);
}

// Round 12
// 98.687 us; speedup vs baseline: 3.5089x; 1.6708x over previous
//
#include <hip/hip_runtime.h>

typedef unsigned short u16;
typedef unsigned long long u64;
typedef __attribute__((ext_vector_type(8))) short short8;   // bf16x8 MFMA fragment
typedef __attribute__((ext_vector_type(4))) short short4v;
typedef __attribute__((ext_vector_type(4))) float f32x4;

#define MFMA16(A,B,C) __builtin_amdgcn_mfma_f32_16x16x32_bf16(A,B,C,0,0,0)
#define NEG_INF_F (-4294967295.0f)

#define Bsz 8
#define Lsz 2048
#define Dsz 128

__device__ __forceinline__ u16 f2bf(float f){
  union { float f; unsigned u; } v; v.f = f;
  unsigned u = v.u;
  return (u16)((u + 0x7fffu + ((u >> 16) & 1u)) >> 16);
}
__device__ __forceinline__ float bf2f(u16 h){
  union { float f; unsigned u; } v; v.u = ((unsigned)h) << 16;
  return v.f;
}
__device__ __forceinline__ short8 lds8(const u16* p){   // 8B-aligned LDS read
  short4v a = *(const short4v*)p;
  short4v b = *(const short4v*)(p + 4);
  short8 r;
  r[0]=a[0]; r[1]=a[1]; r[2]=a[2]; r[3]=a[3];
  r[4]=b[0]; r[5]=b[1]; r[6]=b[2]; r[7]=b[3];
  return r;
}
__device__ __forceinline__ void lds_w16(u16* p, short8 v){
  short4v a, b;
  a[0]=v[0]; a[1]=v[1]; a[2]=v[2]; a[3]=v[3];
  b[0]=v[4]; b[1]=v[5]; b[2]=v[6]; b[3]=v[7];
  *(short4v*)p = a;
  *(short4v*)(p + 4) = b;
}

// ---------------- projection: y = x @ W^T + b, Lorentz map -----------------
#define LPX 136   // bf16 pitch
#define LPY 133   // f32 pitch

__global__ __launch_bounds__(256) void proj_kernel(
    const float* __restrict__ xq, const float* __restrict__ xk, const float* __restrict__ xv,
    const float* __restrict__ Wq, const float* __restrict__ Wk, const float* __restrict__ Wv,
    const float* __restrict__ bq, const float* __restrict__ bk, const float* __restrict__ bv,
    const float* __restrict__ sq, const float* __restrict__ sk, const float* __restrict__ sv,
    const float* __restrict__ attn_scale,
    u16* __restrict__ qout, u16* __restrict__ kout,
    u16* __restrict__ vthi, u16* __restrict__ vtlo,
    float* __restrict__ tqo, float* __restrict__ tko,
    float* __restrict__ vpart)
{
  const int z = blockIdx.z;
  const float* x  = (z == 0) ? xq : (z == 1) ? xk : xv;
  const float* W  = (z == 0) ? Wq : (z == 1) ? Wk : Wv;
  const float* bb = (z == 0) ? bq : (z == 1) ? bk : bv;
  const float* ss = (z == 0) ? sq : (z == 1) ? sk : sv;

  __shared__ u16  xl[64 * LPX];
  __shared__ u16  wl[128 * LPX];
  __shared__ float yl[64 * LPY];
  __shared__ float scl[64];
  __shared__ float tml[64];

  const int t = threadIdx.x;
  const long row0 = (long)blockIdx.x * 64;

  for (int i = t; i < 128 * 128; i += 256) {
    int r = i >> 7, c = i & 127;
    wl[r * LPX + c] = f2bf(W[i]);
  }
  for (int i = t; i < 64 * 128; i += 256) {
    int r = i >> 7, c = i & 127;
    xl[r * LPX + c] = f2bf(x[row0 * 128 + i]);
  }
  __syncthreads();

  const int l = t & 63, wid = t >> 6;
  const int qr = l & 15, g = l >> 4;
  const int r0 = wid * 16;

  short8 af[4];
#pragma unroll
  for (int ks = 0; ks < 4; ks++)
    af[ks] = *(const short8*)&xl[(r0 + qr) * LPX + ks * 32 + g * 8];

  f32x4 acc[8];
#pragma unroll
  for (int jt = 0; jt < 8; jt++) acc[jt] = (f32x4){0.f, 0.f, 0.f, 0.f};

#pragma unroll
  for (int ks = 0; ks < 4; ks++) {
#pragma unroll
    for (int jt = 0; jt < 8; jt++) {
      short8 bfr = *(const short8*)&wl[(jt * 16 + qr) * LPX + ks * 32 + g * 8];
      acc[jt] = MFMA16(af[ks], bfr, acc[jt]);
    }
  }

  float bbv[8];
#pragma unroll
  for (int jt = 0; jt < 8; jt++) bbv[jt] = bb[jt * 16 + qr];

  float ssq[4] = {0.f, 0.f, 0.f, 0.f};
#pragma unroll
  for (int jt = 0; jt < 8; jt++)
#pragma unroll
    for (int r = 0; r < 4; r++) {
      float yv = acc[jt][r] + bbv[jt];
      acc[jt][r] = yv;
      float s2 = yv * yv;
      if (jt == 0) s2 = (qr == 0) ? 0.f : s2;   // exclude d=0
      ssq[r] += s2;
    }
#pragma unroll
  for (int r = 0; r < 4; r++) {
    ssq[r] += __shfl_xor(ssq[r], 1);
    ssq[r] += __shfl_xor(ssq[r], 2);
    ssq[r] += __shfl_xor(ssq[r], 4);
    ssq[r] += __shfl_xor(ssq[r], 8);
  }

  const float es = __expf(ss[0]);
  const float fold = 2.0f / attn_scale[0];

  float tvv[4], sclv[4];
#pragma unroll
  for (int r = 0; r < 4; r++) {
    float y0 = __shfl(acc[0][r], l & 48);     // qr==0 lane of same g: d=0 value
    float tv = es / (1.0f + __expf(-y0)) + 1.1f;
    tvv[r] = tv;
    sclv[r] = sqrtf((tv * tv - 1.0f) / ssq[r]);
  }
  if (qr == 0) {
#pragma unroll
    for (int r = 0; r < 4; r++) {
      tml[r0 + g * 4 + r] = tvv[r];
      scl[r0 + g * 4 + r] = sclv[r];
    }
  }
#pragma unroll
  for (int jt = 0; jt < 8; jt++)
#pragma unroll
    for (int r = 0; r < 4; r++)
      yl[(r0 + g * 4 + r) * LPY + jt * 16 + qr] = acc[jt][r];
  __syncthreads();

  const long gbase = row0 * 128;
  if (z == 0) {
    for (int i = t; i < 64 * 128; i += 256) {
      int r = i >> 7, d = i & 127;
      float v = (d == 0) ? 0.f : yl[r * LPY + d] * scl[r] * fold;
      qout[gbase + i] = f2bf(v);
    }
    if (t < 64) tqo[row0 + t] = -tml[t] * fold;
  } else if (z == 1) {
    for (int i = t; i < 64 * 128; i += 256) {
      int r = i >> 7, d = i & 127;
      float v = (d == 0) ? 0.f : yl[r * LPY + d] * scl[r];
      kout[gbase + i] = f2bf(v);
    }
    if (t < 64) tko[row0 + t] = tml[t];
  } else {
    const int b = (int)(row0 >> 11);
    const int lpos = (int)(row0 & 2047);
    for (int i = t; i < 128 * 64; i += 256) {
      int d = i >> 6, r = i & 63;
      float v = (d == 0) ? tml[r] : yl[r * LPY + d] * scl[r];
      u16 hi = f2bf(v);
      float lo = v - bf2f(hi);
      long idx = ((long)(b * 128 + d)) * 2048 + lpos + r;
      vthi[idx] = hi;
      vtlo[idx] = f2bf(lo);
    }
    if (t < 128) {
      float s = 0.f;
      for (int r = 0; r < 64; r++)
        s += (t == 0) ? tml[r] : yl[r * LPY + t] * scl[r];
      int blk = (int)((row0 >> 6) & 31);
      vpart[((long)(b * 32 + blk)) * 128 + t] = s;
    }
  }
}

// ---------------- pack key-padding mask: one wave per 64-bit word -----------
__global__ __launch_bounds__(256) void pack_mask_kernel(
    const int* __restrict__ mask, u64* __restrict__ pmask)
{
  int gt = blockIdx.x * 256 + threadIdx.x;
  int w = gt >> 6;
  int lane = gt & 63;
  if (w >= Bsz * 32) return;
  u64 word = __ballot(mask[w * 64 + lane] != 0);
  if (lane == 0) pmask[w] = word;
}

// ---------------- deterministic v-sum reduce --------------------------------
__global__ __launch_bounds__(128) void vreduce_kernel(
    const float* __restrict__ vpart, float* __restrict__ vsum)
{
  int i = blockIdx.x * 128 + threadIdx.x;
  int b = i >> 7, d = i & 127;
  float s = 0.f;
  for (int j = 0; j < 32; j++) s += vpart[((long)(b * 32 + j)) * 128 + d];
  vsum[i] = s;
}

// ---------------- flash attention + Lorentz epilogue ------------------------
// Block = 512 thr = ONE 32-row strip: 2 q-subs x 4 waves. K(16KB) + Vhi/Vlo
// (32KB) staged ONCE per tile into LDS (reg-staged, parity dbuf), consumed by
// both subs -> 2x L2 traffic cut, LDS-latency chains. Per-sub engine = r9
// cooperative (wave w QKs keys [16w,+16), LDS stat exchange, shared P tile,
// PV d-sliced). Perfect balance: block p runs strip 63-p then strip p -> 33
// tiles for EVERY block; grid 256 = 1 block/CU, zero drain. b = blk&7 (XCD).
#define KP 132   // K LDS pitch (u16): 264B rows, 8B-aligned, odd-ish banks
#define VP 68    // V LDS pitch (u16): 136B rows

__global__ __launch_bounds__(512, 2) void flash_kernel(
    const u16* __restrict__ qb, const u16* __restrict__ kb,
    const u16* __restrict__ vthi, const u16* __restrict__ vtlo,
    const float* __restrict__ tq, const float* __restrict__ tk,
    const u64* __restrict__ pmask, const float* __restrict__ vsum,
    float* __restrict__ out)
{
  __shared__ u16 Kl[2][64 * KP];        // 33.8 KB
  __shared__ u16 Vh[2][128 * VP];       // 34.8 KB
  __shared__ u16 Vl[2][128 * VP];       // 34.8 KB
  __shared__ u16 Pl[2][2][16 * 72];     // [sub][parity]  9.2 KB
  __shared__ float mstat[2][2][4][16];  // [sub][parity][wave][q]
  __shared__ float lLd[2][4][16];
  __shared__ float ssqw[2][4][16];

  const int t = threadIdx.x;
  const int w8 = t >> 6, l = t & 63;
  const int sub = w8 >> 2, w = w8 & 3;
  const int qr = l & 15, g = l >> 4;
  const int blk = blockIdx.x;
  const int b = blk & 7;                // batch == XCD (round-robin dispatch)
  const int pr = blk >> 3;              // 0..31 pair index

  // staging coords (constant per thread): K 2 chunks, Vhi 2, Vlo 2
  const int krow = t >> 4, kcol = (t & 15) * 8;        // + row 32 for chunk 2
  const int vrow = t >> 3, vcol = (t & 7) * 8;         // + row 64 for chunk 2
  const int klds = krow * KP + kcol;
  const int vlds = vrow * VP + vcol;

  for (int phase = 0; phase < 2; ++phase) {
    const int st = phase ? pr : (63 - pr);
    const int qbase = st * 32;
    const int q0s = qbase + sub * 16;   // min q-row of this sub
    const int qg  = q0s + qr;
    const int nkt = (st >> 1) + 1;      // 64-key tiles covering [0, qbase+32)

    const u16* qptr = qb + ((long)(b * 2048 + qg)) * 128 + g * 8;
    short8 qf[4];
#pragma unroll
    for (int ks = 0; ks < 4; ks++) qf[ks] = *(const short8*)(qptr + ks * 32);
    const float tqv = tq[b * 2048 + qg];

    float m = NEG_INF_F, lsum = 0.f;
    f32x4 acc[2];
    acc[0] = (f32x4){0.f, 0.f, 0.f, 0.f};
    acc[1] = (f32x4){0.f, 0.f, 0.f, 0.f};

    // ---- prologue: stage tile 0 into buffer 0 ----
    {
      const long kg = (long)(b * 2048 + krow) * 128 + kcol;
      const long vg = (long)(b * 128 + vrow) * 2048 + vcol;
      short8 s0 = *(const short8*)(kb + kg);
      short8 s1 = *(const short8*)(kb + kg + (long)32 * 128);
      short8 s2 = *(const short8*)(vthi + vg);
      short8 s3 = *(const short8*)(vthi + vg + (long)64 * 2048);
      short8 s4 = *(const short8*)(vtlo + vg);
      short8 s5 = *(const short8*)(vtlo + vg + (long)64 * 2048);
      lds_w16(&Kl[0][klds], s0);
      lds_w16(&Kl[0][klds + 32 * KP], s1);
      lds_w16(&Vh[0][vlds], s2);
      lds_w16(&Vh[0][vlds + 64 * VP], s3);
      lds_w16(&Vl[0][vlds], s4);
      lds_w16(&Vl[0][vlds + 64 * VP], s5);
    }
    __syncthreads();

    for (int kt = 0; kt < nkt; ++kt) {
      const int k0 = kt << 6;
      const int cur = kt & 1;
      const bool more = (kt + 1 < nkt);

      // early: global loads for tile kt+1 (land during both segments)
      short8 s0, s1, s2, s3, s4, s5;
      if (more) {
        const int nk = k0 + 64;
        const long kg = (long)(b * 2048 + nk + krow) * 128 + kcol;
        const long vg = (long)(b * 128 + vrow) * 2048 + nk + vcol;
        s0 = *(const short8*)(kb + kg);
        s1 = *(const short8*)(kb + kg + (long)32 * 128);
        s2 = *(const short8*)(vthi + vg);
        s3 = *(const short8*)(vthi + vg + (long)64 * 2048);
        s4 = *(const short8*)(vtlo + vg);
        s5 = *(const short8*)(vtlo + vg + (long)64 * 2048);
      }

      // ---- segment A: PV(kt-1) from buf cur^1 + QK(kt) from buf cur ----
      __builtin_amdgcn_s_setprio(1);
      if (kt > 0) {
        const int pv = cur ^ 1;
        short8 pf0 = *(const short8*)&Pl[sub][pv][qr * 72 + g * 8];
        short8 pf1 = *(const short8*)&Pl[sub][pv][qr * 72 + 32 + g * 8];
#pragma unroll
        for (int j = 0; j < 2; j++) {
          const int vr = (32 * w + 16 * j + qr) * VP + g * 8;
          acc[j] = MFMA16(lds8(&Vh[pv][vr]), pf0, acc[j]);
          acc[j] = MFMA16(lds8(&Vl[pv][vr]), pf0, acc[j]);
          acc[j] = MFMA16(lds8(&Vh[pv][vr + 32]), pf1, acc[j]);
          acc[j] = MFMA16(lds8(&Vl[pv][vr + 32]), pf1, acc[j]);
        }
      }
      f32x4 sv = (f32x4){0.f, 0.f, 0.f, 0.f};
      {
        const u16* kr = &Kl[cur][(16 * w + qr) * KP + g * 8];
#pragma unroll
        for (int ks = 0; ks < 4; ks++)
          sv = MFMA16(lds8(kr + ks * 32), qf[ks], sv);
      }
      __builtin_amdgcn_s_setprio(0);

      const u64 mw = pmask[b * 32 + kt];
      f32x4 tkv = *(const f32x4*)(tk + b * 2048 + k0 + 16 * w + g * 4);
      const bool bndry = (k0 + 63 > q0s);

      float p4[4];
      float tmax = NEG_INF_F;
#pragma unroll
      for (int r = 0; r < 4; r++) {
        int kl = 16 * w + g * 4 + r;
        float val = sv[r] + tqv * tkv[r];       // exact fp32 time product
        bool bad = ((mw >> kl) & 1ull) != 0ull;
        if (bndry) bad |= (k0 + kl > qg);
        val = bad ? NEG_INF_F : val;
        p4[r] = val;
        tmax = fmaxf(tmax, val);
      }
      tmax = fmaxf(tmax, __shfl_xor(tmax, 16));
      tmax = fmaxf(tmax, __shfl_xor(tmax, 32));
      if (g == 0) mstat[sub][cur][w][qr] = tmax;
      __syncthreads();                          // B1

      // ---- segment B: softmax finish + P write + staged LDS writes ----
      float mt = fmaxf(fmaxf(mstat[sub][cur][0][qr], mstat[sub][cur][1][qr]),
                       fmaxf(mstat[sub][cur][2][qr], mstat[sub][cur][3][qr]));
      float mn = fmaxf(m, mt);
      float rr = __expf(m - mn);
      m = mn;

      float ts = 0.f;
#pragma unroll
      for (int r = 0; r < 4; r++) {
        float pv = __expf(p4[r] - mn);
        p4[r] = pv;
        ts += pv;
      }
      {
        u64 wv = (u64)f2bf(p4[0])
               | ((u64)f2bf(p4[1]) << 16)
               | ((u64)f2bf(p4[2]) << 32)
               | ((u64)f2bf(p4[3]) << 48);
        *(u64*)&Pl[sub][cur][qr * 72 + 16 * w + g * 4] = wv;
      }
      lsum = lsum * rr + ts;
      acc[0][0] *= rr; acc[0][1] *= rr; acc[0][2] *= rr; acc[0][3] *= rr;
      acc[1][0] *= rr; acc[1][1] *= rr; acc[1][2] *= rr; acc[1][3] *= rr;

      if (more) {                               // write tile kt+1 into buf cur^1
        const int nb = cur ^ 1;
        lds_w16(&Kl[nb][klds], s0);
        lds_w16(&Kl[nb][klds + 32 * KP], s1);
        lds_w16(&Vh[nb][vlds], s2);
        lds_w16(&Vh[nb][vlds + 64 * VP], s3);
        lds_w16(&Vl[nb][vlds], s4);
        lds_w16(&Vl[nb][vlds + 64 * VP], s5);
      }
      __syncthreads();                          // B2
    }

    // ---- final PV (last tile) ----
    {
      const int pv = (nkt - 1) & 1;
      short8 pf0 = *(const short8*)&Pl[sub][pv][qr * 72 + g * 8];
      short8 pf1 = *(const short8*)&Pl[sub][pv][qr * 72 + 32 + g * 8];
#pragma unroll
      for (int j = 0; j < 2; j++) {
        const int vr = (32 * w + 16 * j + qr) * VP + g * 8;
        acc[j] = MFMA16(lds8(&Vh[pv][vr]), pf0, acc[j]);
        acc[j] = MFMA16(lds8(&Vl[pv][vr]), pf0, acc[j]);
        acc[j] = MFMA16(lds8(&Vh[pv][vr + 32]), pf1, acc[j]);
        acc[j] = MFMA16(lds8(&Vl[pv][vr + 32]), pf1, acc[j]);
      }
    }

    // ---- epilogue (per sub): lsum merge + Lorentz normalize ----
    lsum += __shfl_xor(lsum, 16);
    lsum += __shfl_xor(lsum, 32);
    if (g == 0) lLd[sub][w][qr] = lsum;
    __syncthreads();

    float Lt = lLd[sub][0][qr] + lLd[sub][1][qr]
             + lLd[sub][2][qr] + lLd[sub][3][qr];
    const bool mrow = (m == NEG_INF_F);   // row fully masked -> uniform over ALL keys
    float invL = mrow ? 0.f : 1.0f / Lt;

    const float* vs = vsum + b * 128;
    float av[8];
    float pp = 0.f;
#pragma unroll
    for (int j = 0; j < 2; j++)
#pragma unroll
      for (int r = 0; r < 4; r++) {
        int d = 32 * w + 16 * j + g * 4 + r;
        float a = mrow ? vs[d] * (1.0f / 2048.0f) : acc[j][r] * invL;
        av[j * 4 + r] = a;
        pp += (d == 0) ? -a * a : a * a;
      }
    pp += __shfl_xor(pp, 16);
    pp += __shfl_xor(pp, 32);
    if (g == 0) ssqw[sub][w][qr] = pp;
    __syncthreads();

    float lor = ssqw[sub][0][qr] + ssqw[sub][1][qr]
              + ssqw[sub][2][qr] + ssqw[sub][3][qr];
    float rd = 1.0f / sqrtf(fmaxf(fabsf(lor), 1e-8f));

    float* op = out + ((long)(b * 2048 + qg)) * 128;
#pragma unroll
    for (int j = 0; j < 2; j++) {
      f32x4 o;
      o[0] = av[j * 4 + 0] * rd; o[1] = av[j * 4 + 1] * rd;
      o[2] = av[j * 4 + 2] * rd; o[3] = av[j * 4 + 3] * rd;
      *(f32x4*)&op[32 * w + 16 * j + g * 4] = o;
    }
    __syncthreads();   // LDS safe for next phase's prologue
  }
}

// ---------------- launch ----------------------------------------------------
extern "C" void kernel_launch(void* const* d_in, const int* in_sizes, int n_in,
                              void* d_out, int out_size, void* d_ws, size_t ws_size,
                              hipStream_t stream)
{
  const float* query = (const float*)d_in[0];
  const float* key   = (const float*)d_in[1];
  const float* value = (const float*)d_in[2];
  const int*   mask  = (const int*)d_in[3];
  const float* Wq = (const float*)d_in[4];
  const float* bq = (const float*)d_in[5];
  const float* sq = (const float*)d_in[6];
  const float* Wk = (const float*)d_in[7];
  const float* bk = (const float*)d_in[8];
  const float* sk = (const float*)d_in[9];
  const float* Wv = (const float*)d_in[10];
  const float* bv = (const float*)d_in[11];
  const float* sv = (const float*)d_in[12];
  const float* attn_scale = (const float*)d_in[13];
  // d_in[14] = attn_bias: cancels in softmax, unused

  float* out = (float*)d_out;
  char* ws = (char*)d_ws;

  float* vsum  = (float*)ws;                        // 4 KB
  u64*   pmask = (u64*)(ws + 4096);                 // 2 KB (pad to 4 KB)
  float* tqa   = (float*)(ws + 8192);               // 64 KB
  float* tka   = (float*)(ws + 8192 + 65536);       // 64 KB
  float* vpart = (float*)(ws + 8192 + 131072);      // 128 KB
  char*  big   = ws + 8192 + 131072 + 131072;
  u16*   qbuf  = (u16*)big;                         // 4 MB
  u16*   kbuf  = qbuf + (size_t)16384 * 128;        // 4 MB
  u16*   vthi  = kbuf + (size_t)16384 * 128;        // 4 MB
  u16*   vtlo  = vthi + (size_t)16384 * 128;        // 4 MB

  proj_kernel<<<dim3(256, 1, 3), 256, 0, stream>>>(
      query, key, value, Wq, Wk, Wv, bq, bk, bv, sq, sk, sv, attn_scale,
      qbuf, kbuf, vthi, vtlo, tqa, tka, vpart);
  pack_mask_kernel<<<64, 256, 0, stream>>>(mask, pmask);
  vreduce_kernel<<<8, 128, 0, stream>>>(vpart, vsum);
  flash_kernel<<<256, 512, 0, stream>>>(
      qbuf, kbuf, vthi, vtlo, tqa, tka, pmask, vsum, out);
}